// Round 9
// baseline (962.774 us; speedup 1.0000x reference)
//
#include <hip/hip_runtime.h>
#include <hip/hip_bf16.h>

#define N_NODES 100000
#define N_EDGES 600000
#define N_GRAPHS 64
#define D 128

#define NBLK_SCAN ((N_NODES + 255) / 256)  // 391

// ---------------- CSR build ----------------

__global__ void count_deg_k(const int* __restrict__ col, int* __restrict__ cnt) {
    int e = blockIdx.x * blockDim.x + threadIdx.x;
    if (e < N_EDGES) atomicAdd(&cnt[col[e]], 1);
}

__global__ __launch_bounds__(256) void partial_k(const int* __restrict__ cnt,
                                                 int* __restrict__ psum) {
    int i = blockIdx.x * 256 + threadIdx.x;
    int v = (i < N_NODES) ? cnt[i] : 0;
#pragma unroll
    for (int d = 32; d > 0; d >>= 1) v += __shfl_down(v, d, 64);
    __shared__ int ws[4];
    if ((threadIdx.x & 63) == 0) ws[threadIdx.x >> 6] = v;
    __syncthreads();
    if (threadIdx.x == 0) psum[blockIdx.x] = ws[0] + ws[1] + ws[2] + ws[3];
}

__global__ __launch_bounds__(512) void scanpart_k(int* __restrict__ psum) {
    __shared__ int ls[512];
    int t = threadIdx.x;
    int v = (t < NBLK_SCAN) ? psum[t] : 0;
    ls[t] = v;
    __syncthreads();
    for (int d = 1; d < 512; d <<= 1) {
        int u = (t >= d) ? ls[t - d] : 0;
        __syncthreads();
        ls[t] += u;
        __syncthreads();
    }
    if (t < NBLK_SCAN) psum[t] = ls[t] - v;  // exclusive
}

__global__ __launch_bounds__(256) void scan_scatter_k(const int* __restrict__ cnt,
                                                      const int* __restrict__ psum,
                                                      int* __restrict__ start) {
    int b = blockIdx.x, t = threadIdx.x;
    int i = b * 256 + t;
    int v = (i < N_NODES) ? cnt[i] : 0;
    __shared__ int ls[256];
    ls[t] = v;
    __syncthreads();
    for (int d = 1; d < 256; d <<= 1) {
        int u = (t >= d) ? ls[t - d] : 0;
        __syncthreads();
        ls[t] += u;
        __syncthreads();
    }
    int incl = ls[t];
    int off = psum[b];
    if (i < N_NODES) start[i] = off + incl - v;
    if (i == N_NODES - 1) start[N_NODES] = off + incl;
}

__global__ void fill_csr_k(const int* __restrict__ row, const int* __restrict__ col,
                           const int* __restrict__ start, int* __restrict__ fill,
                           int* __restrict__ esrc) {
    int e = blockIdx.x * blockDim.x + threadIdx.x;
    if (e < N_EDGES) {
        int c = col[e];
        int p = atomicAdd(&fill[c], 1);
        esrc[start[c] + p] = row[e];
    }
}

// ---------------- graph segment bounds (batch is sorted) ----------------

__global__ __launch_bounds__(128) void bounds_k(const int* __restrict__ batch,
                                                int* __restrict__ gstart) {
    int g = threadIdx.x;
    if (g > N_GRAPHS) return;
    int lo = 0, hi = N_NODES;
    while (lo < hi) {
        int mid = (lo + hi) >> 1;
        if (batch[mid] < g) lo = mid + 1; else hi = mid;
    }
    gstart[g] = lo;
}

// ---------------- GEMM: out[i][j] = bias[j] + sum_k in[i][k]*W[j][k] ----------------
// Round-3 compute/store mapping (rows 8ty+i, cols 8tx+r, float4 global stores)
// + round-5-verified swizzled global_load_lds staging, single-buffered 32KB LDS.
// LDS layout: tile [128 rows][32 floats]; slot c4' of row holds global chunk
// c4'^s4(row), s4(row) = ((row>>3)^row)&7. Reads:
//   A row 8ty+i -> slot c4 ^ ((ty^i)&7)  : 4 broadcast addrs/wave -> free
//   W row 8tx+r -> slot c4 ^ ((tx^r)&7)  : 2-way over 16 tx -> free

#define BM 128
#define KT 32

__device__ __forceinline__ void stage32(const float* __restrict__ G, float* lds,
                                        int grow0, int kb, int nrows, int tid) {
    int l = tid & 63, w = tid >> 6;
#pragma unroll
    for (int i = 0; i < 4; ++i) {
        int f = (w + i * 4) * 64 + l;  // float4 task 0..1023
        int row = f >> 3, c4 = f & 7;
        int s4 = ((row >> 3) ^ row) & 7;
        const float* gp = G + (size_t)(grow0 + row) * D + kb + ((c4 ^ s4) << 2);
        float* lp = lds + (w + i * 4) * 256;  // wave-uniform; HW adds lane*16B
        if (grow0 + row < nrows)
            __builtin_amdgcn_global_load_lds(
                (const __attribute__((address_space(1))) void*)gp,
                (__attribute__((address_space(3))) void*)lp, 16, 0, 0);
    }
}

__global__ __launch_bounds__(256, 4) void gemm_k(const float* __restrict__ A,
                                                 const float* __restrict__ W,
                                                 const float* __restrict__ bias,
                                                 float* __restrict__ out, int nrows) {
    __shared__ float sA[BM * KT];  // 16KB
    __shared__ float sW[BM * KT];  // 16KB
    const int tid = threadIdx.x;
    const int bm0 = blockIdx.x * BM;
    const int tx = tid & 15, ty = tid >> 4;

    float acc[8][8];
#pragma unroll
    for (int i = 0; i < 8; ++i)
#pragma unroll
        for (int r = 0; r < 8; ++r) acc[i][r] = 0.f;

    float bv[8];
#pragma unroll
    for (int r = 0; r < 8; ++r) bv[r] = bias[8 * tx + r];

    for (int kt = 0; kt < D / KT; ++kt) {
        stage32(A, sA, bm0, kt * KT, nrows, tid);
        stage32(W, sW, 0, kt * KT, D, tid);
        __syncthreads();  // drains vmcnt (gload_lds) for all waves
#pragma unroll
        for (int c4 = 0; c4 < 8; ++c4) {
            float4 a[8], w[8];
#pragma unroll
            for (int i = 0; i < 8; ++i)
                a[i] = *reinterpret_cast<const float4*>(
                    &sA[(8 * ty + i) * KT + ((c4 ^ ((ty ^ i) & 7)) << 2)]);
#pragma unroll
            for (int r = 0; r < 8; ++r)
                w[r] = *reinterpret_cast<const float4*>(
                    &sW[(8 * tx + r) * KT + ((c4 ^ ((tx ^ r) & 7)) << 2)]);
#pragma unroll
            for (int i = 0; i < 8; ++i)
#pragma unroll
                for (int r = 0; r < 8; ++r) {
                    acc[i][r] = fmaf(a[i].x, w[r].x, acc[i][r]);
                    acc[i][r] = fmaf(a[i].y, w[r].y, acc[i][r]);
                    acc[i][r] = fmaf(a[i].z, w[r].z, acc[i][r]);
                    acc[i][r] = fmaf(a[i].w, w[r].w, acc[i][r]);
                }
        }
        __syncthreads();  // protect LDS before next stage
    }

#pragma unroll
    for (int i = 0; i < 8; ++i) {
        int grow = bm0 + ty * 8 + i;
        if (grow >= nrows) continue;
        float4 o0 = make_float4(acc[i][0] + bv[0], acc[i][1] + bv[1],
                                acc[i][2] + bv[2], acc[i][3] + bv[3]);
        float4 o1 = make_float4(acc[i][4] + bv[4], acc[i][5] + bv[5],
                                acc[i][6] + bv[6], acc[i][7] + bv[7]);
        *reinterpret_cast<float4*>(&out[(size_t)grow * D + tx * 8]) = o0;
        *reinterpret_cast<float4*>(&out[(size_t)grow * D + tx * 8 + 4]) = o1;
    }
}

// ---------------- Aggregation: out[i] = t[i] + sum_{e: col==i} t[src[e]] ----------------
// Grid-strided persistent blocks (2 nodes per 256-thread block per iter) to
// remove the 100k-tiny-block launch overhead.

#define AGG_BLOCKS 2048

__global__ __launch_bounds__(256) void aggregate_k(const float* __restrict__ t,
                                                   const int* __restrict__ start,
                                                   const int* __restrict__ esrc,
                                                   float* __restrict__ out, int do_relu) {
    const int d = threadIdx.x & 127;
    const int sub = threadIdx.x >> 7;  // 0..1 (wave-pair uniform)
    for (int node = blockIdx.x * 2 + sub; node < N_NODES; node += AGG_BLOCKS * 2) {
        int s = start[node], e = start[node + 1];
        float acc = t[(size_t)node * D + d];  // self loop
        int i = s;
        for (; i + 1 < e; i += 2) {
            int s0 = esrc[i], s1 = esrc[i + 1];
            float a = t[(size_t)s0 * D + d];
            float b = t[(size_t)s1 * D + d];
            acc += a + b;
        }
        if (i < e) acc += t[(size_t)esrc[i] * D + d];
        if (do_relu) acc = fmaxf(acc, 0.f);
        out[(size_t)node * D + d] = acc;
    }
}

// ---------------- Collapsed layer 4 + pool + head ----------------
// logit_g = (1/c_g) * sum_{i in g} [ s[i] + sum_{src->i} s[src] + (1+deg_i)*beta ] + bc
// where s[i] = h3[i] . v,  v = Wc @ W4,  beta = Wc . b4.

__global__ __launch_bounds__(128) void vbeta_k(const float* __restrict__ W4,
                                               const float* __restrict__ b4,
                                               const float* __restrict__ Wc,
                                               float* __restrict__ vbeta) {
    int k = threadIdx.x;
    float acc = 0.f;
    for (int j = 0; j < D; ++j) acc = fmaf(Wc[j], W4[j * D + k], acc);
    vbeta[k] = acc;
    __shared__ float red[128];
    red[k] = Wc[k] * b4[k];
    __syncthreads();
    for (int st = 64; st > 0; st >>= 1) {
        if (k < st) red[k] += red[k + st];
        __syncthreads();
    }
    if (k == 0) vbeta[D] = red[0];
}

__global__ __launch_bounds__(256) void matvec_k(const float* __restrict__ h,
                                                const float* __restrict__ vbeta,
                                                float* __restrict__ s) {
    int wid = threadIdx.x >> 6, lane = threadIdx.x & 63;
    int row = blockIdx.x * 4 + wid;
    const float2 hv = *reinterpret_cast<const float2*>(&h[(size_t)row * D + lane * 2]);
    const float2 vv = *reinterpret_cast<const float2*>(&vbeta[lane * 2]);
    float dot = fmaf(hv.x, vv.x, hv.y * vv.y);
#pragma unroll
    for (int d = 32; d > 0; d >>= 1) dot += __shfl_down(dot, d, 64);
    if (lane == 0) s[row] = dot;
}

__global__ __launch_bounds__(256) void sagg_k(const float* __restrict__ s,
                                              const int* __restrict__ start,
                                              const int* __restrict__ esrc,
                                              const float* __restrict__ vbeta,
                                              float* __restrict__ a) {
    int i = blockIdx.x * 256 + threadIdx.x;
    if (i >= N_NODES) return;
    int s0 = start[i], s1 = start[i + 1];
    float beta = vbeta[D];
    float acc = s[i] + (float)(1 + s1 - s0) * beta;
    for (int e = s0; e < s1; ++e) acc += s[esrc[e]];
    a[i] = acc;
}

__global__ __launch_bounds__(256) void spool_k(const float* __restrict__ a,
                                               const int* __restrict__ gstart,
                                               const float* __restrict__ bc,
                                               float* __restrict__ out) {
    int g = blockIdx.x;
    int lo = gstart[g], hi = gstart[g + 1];
    float acc = 0.f;
    for (int i = lo + threadIdx.x; i < hi; i += 256) acc += a[i];
    __shared__ float red[256];
    red[threadIdx.x] = acc;
    __syncthreads();
    for (int st = 128; st > 0; st >>= 1) {
        if (threadIdx.x < st) red[threadIdx.x] += red[threadIdx.x + st];
        __syncthreads();
    }
    if (threadIdx.x == 0) {
        float c = (float)max(hi - lo, 1);
        out[g] = 1.f / (1.f + expf(-(red[0] / c + bc[0])));
    }
}

// ---------------- Launch ----------------

extern "C" void kernel_launch(void* const* d_in, const int* in_sizes, int n_in,
                              void* d_out, int out_size, void* d_ws, size_t ws_size,
                              hipStream_t stream) {
    const float* x   = (const float*)d_in[0];
    const int* ei    = (const int*)d_in[1];
    const int* batch = (const int*)d_in[2];
    const float* W1  = (const float*)d_in[3];
    const float* b1  = (const float*)d_in[4];
    const float* W2  = (const float*)d_in[5];
    const float* b2  = (const float*)d_in[6];
    const float* W3  = (const float*)d_in[7];
    const float* b3  = (const float*)d_in[8];
    const float* W4  = (const float*)d_in[9];
    const float* b4  = (const float*)d_in[10];
    const float* Wc  = (const float*)d_in[11];
    const float* bc  = (const float*)d_in[12];
    float* out = (float*)d_out;

    const int* row = ei;             // sources
    const int* col = ei + N_EDGES;   // targets

    char* p = (char*)d_ws;
    float* t = (float*)p;      p += (size_t)N_NODES * D * 4;   // 51.2 MB
    float* h = (float*)p;      p += (size_t)N_NODES * D * 4;   // 51.2 MB
    int* esrc = (int*)p;       p += (size_t)N_EDGES * 4;
    int* cstart = (int*)p;     p += ((N_NODES + 1) * 4 + 15) / 16 * 16;
    int* cfill = (int*)p;      p += (size_t)N_NODES * 4;
    int* psum = (int*)p;       p += ((NBLK_SCAN + 3) / 4) * 16;
    int* gstart = (int*)p;     p += 256;

    // scalar-path scratch lives in t (free after layer-3 aggregate consumes it)
    float* vbeta = t;
    float* s_arr = t + 256;
    float* a_arr = t + 256 + N_NODES;

    // ---- CSR build ----
    hipMemsetAsync(cfill, 0, (size_t)N_NODES * 4, stream);
    count_deg_k<<<(N_EDGES + 255) / 256, 256, 0, stream>>>(col, cfill);
    partial_k<<<NBLK_SCAN, 256, 0, stream>>>(cfill, psum);
    scanpart_k<<<1, 512, 0, stream>>>(psum);
    scan_scatter_k<<<NBLK_SCAN, 256, 0, stream>>>(cfill, psum, cstart);
    hipMemsetAsync(cfill, 0, (size_t)N_NODES * 4, stream);
    fill_csr_k<<<(N_EDGES + 255) / 256, 256, 0, stream>>>(row, col, cstart, cfill, esrc);

    // ---- graph bounds ----
    bounds_k<<<1, 128, 0, stream>>>(batch, gstart);

    const int ggrid = (N_NODES + BM - 1) / BM;  // 782

    // ---- Layers 1-3 ----
    gemm_k<<<ggrid, 256, 0, stream>>>(x, W1, b1, t, N_NODES);
    aggregate_k<<<AGG_BLOCKS, 256, 0, stream>>>(t, cstart, esrc, h, 1);
    gemm_k<<<ggrid, 256, 0, stream>>>(h, W2, b2, t, N_NODES);
    aggregate_k<<<AGG_BLOCKS, 256, 0, stream>>>(t, cstart, esrc, h, 1);
    gemm_k<<<ggrid, 256, 0, stream>>>(h, W3, b3, t, N_NODES);
    aggregate_k<<<AGG_BLOCKS, 256, 0, stream>>>(t, cstart, esrc, h, 1);

    // ---- Collapsed layer 4 + pool + head (reads h = h3) ----
    vbeta_k<<<1, 128, 0, stream>>>(W4, b4, Wc, vbeta);
    matvec_k<<<N_NODES / 4, 256, 0, stream>>>(h, vbeta, s_arr);
    sagg_k<<<(N_NODES + 255) / 256, 256, 0, stream>>>(s_arr, cstart, esrc, vbeta, a_arr);
    spool_k<<<N_GRAPHS, 256, 0, stream>>>(a_arr, gstart, bc, out);
}

// Round 10
// 513.651 us; speedup vs baseline: 1.8744x; 1.8744x over previous
//
#include <hip/hip_runtime.h>
#include <hip/hip_bf16.h>

#define N_NODES 100000
#define N_EDGES 600000
#define N_GRAPHS 64
#define D 128

#define NBLK_SCAN ((N_NODES + 255) / 256)  // 391

// ---------------- CSR build ----------------

__global__ void count_deg_k(const int* __restrict__ col, int* __restrict__ cnt) {
    int e = blockIdx.x * blockDim.x + threadIdx.x;
    if (e < N_EDGES) atomicAdd(&cnt[col[e]], 1);
}

__global__ __launch_bounds__(256) void partial_k(const int* __restrict__ cnt,
                                                 int* __restrict__ psum) {
    int i = blockIdx.x * 256 + threadIdx.x;
    int v = (i < N_NODES) ? cnt[i] : 0;
#pragma unroll
    for (int d = 32; d > 0; d >>= 1) v += __shfl_down(v, d, 64);
    __shared__ int ws[4];
    if ((threadIdx.x & 63) == 0) ws[threadIdx.x >> 6] = v;
    __syncthreads();
    if (threadIdx.x == 0) psum[blockIdx.x] = ws[0] + ws[1] + ws[2] + ws[3];
}

__global__ __launch_bounds__(512) void scanpart_k(int* __restrict__ psum) {
    __shared__ int ls[512];
    int t = threadIdx.x;
    int v = (t < NBLK_SCAN) ? psum[t] : 0;
    ls[t] = v;
    __syncthreads();
    for (int d = 1; d < 512; d <<= 1) {
        int u = (t >= d) ? ls[t - d] : 0;
        __syncthreads();
        ls[t] += u;
        __syncthreads();
    }
    if (t < NBLK_SCAN) psum[t] = ls[t] - v;  // exclusive
}

__global__ __launch_bounds__(256) void scan_scatter_k(const int* __restrict__ cnt,
                                                      const int* __restrict__ psum,
                                                      int* __restrict__ start) {
    int b = blockIdx.x, t = threadIdx.x;
    int i = b * 256 + t;
    int v = (i < N_NODES) ? cnt[i] : 0;
    __shared__ int ls[256];
    ls[t] = v;
    __syncthreads();
    for (int d = 1; d < 256; d <<= 1) {
        int u = (t >= d) ? ls[t - d] : 0;
        __syncthreads();
        ls[t] += u;
        __syncthreads();
    }
    int incl = ls[t];
    int off = psum[b];
    if (i < N_NODES) start[i] = off + incl - v;
    if (i == N_NODES - 1) start[N_NODES] = off + incl;
}

__global__ void fill_csr_k(const int* __restrict__ row, const int* __restrict__ col,
                           const int* __restrict__ start, int* __restrict__ fill,
                           int* __restrict__ esrc) {
    int e = blockIdx.x * blockDim.x + threadIdx.x;
    if (e < N_EDGES) {
        int c = col[e];
        int p = atomicAdd(&fill[c], 1);
        esrc[start[c] + p] = row[e];
    }
}

// ---------------- graph segment bounds (batch is sorted) ----------------

__global__ __launch_bounds__(128) void bounds_k(const int* __restrict__ batch,
                                                int* __restrict__ gstart) {
    int g = threadIdx.x;
    if (g > N_GRAPHS) return;
    int lo = 0, hi = N_NODES;
    while (lo < hi) {
        int mid = (lo + hi) >> 1;
        if (batch[mid] < g) lo = mid + 1; else hi = mid;
    }
    gstart[g] = lo;
}

// ---------------- GEMM: out[i][j] = bias[j] + sum_k in[i][k]*W[j][k] ----------------
// Round-8 structure with the spill fixed: __launch_bounds__(256,2) (round-5's
// proven no-spill config; (256,4) capped VGPRs at 64 -> acc[8][8] spilled to
// scratch -> 738MB/dispatch of scratch traffic, 250us).
// LDS layout: tile [128 rows][32 floats]; slot c4' of row holds global chunk
// c4'^s4(row), s4(row) = ((row>>3)^row)&7. Reads:
//   A row 8ty+i -> slot c4 ^ ((ty^i)&7)  : 4 broadcast addrs/wave -> free
//   W row 8tx+r -> slot c4 ^ ((tx^r)&7)  : 2-way over 16 tx -> free (m136)

#define BM 128
#define KT 32

__device__ __forceinline__ void stage32(const float* __restrict__ G, float* lds,
                                        int grow0, int kb, int nrows, int tid) {
    int l = tid & 63, w = tid >> 6;
#pragma unroll
    for (int i = 0; i < 4; ++i) {
        int f = (w + i * 4) * 64 + l;  // float4 task 0..1023
        int row = f >> 3, c4 = f & 7;
        int s4 = ((row >> 3) ^ row) & 7;
        const float* gp = G + (size_t)(grow0 + row) * D + kb + ((c4 ^ s4) << 2);
        float* lp = lds + (w + i * 4) * 256;  // wave-uniform; HW adds lane*16B
        if (grow0 + row < nrows)
            __builtin_amdgcn_global_load_lds(
                (const __attribute__((address_space(1))) void*)gp,
                (__attribute__((address_space(3))) void*)lp, 16, 0, 0);
    }
}

__global__ __launch_bounds__(256, 2) void gemm_k(const float* __restrict__ A,
                                                 const float* __restrict__ W,
                                                 const float* __restrict__ bias,
                                                 float* __restrict__ out, int nrows) {
    __shared__ float sA[BM * KT];  // 16KB
    __shared__ float sW[BM * KT];  // 16KB
    const int tid = threadIdx.x;
    const int bm0 = blockIdx.x * BM;
    const int tx = tid & 15, ty = tid >> 4;

    float acc[8][8];
#pragma unroll
    for (int i = 0; i < 8; ++i)
#pragma unroll
        for (int r = 0; r < 8; ++r) acc[i][r] = 0.f;

    float bv[8];
#pragma unroll
    for (int r = 0; r < 8; ++r) bv[r] = bias[8 * tx + r];

    for (int kt = 0; kt < D / KT; ++kt) {
        stage32(A, sA, bm0, kt * KT, nrows, tid);
        stage32(W, sW, 0, kt * KT, D, tid);
        __syncthreads();  // drains vmcnt (gload_lds) for all waves
#pragma unroll
        for (int c4 = 0; c4 < 8; ++c4) {
            float4 a[8], w[8];
#pragma unroll
            for (int i = 0; i < 8; ++i)
                a[i] = *reinterpret_cast<const float4*>(
                    &sA[(8 * ty + i) * KT + ((c4 ^ ((ty ^ i) & 7)) << 2)]);
#pragma unroll
            for (int r = 0; r < 8; ++r)
                w[r] = *reinterpret_cast<const float4*>(
                    &sW[(8 * tx + r) * KT + ((c4 ^ ((tx ^ r) & 7)) << 2)]);
#pragma unroll
            for (int i = 0; i < 8; ++i)
#pragma unroll
                for (int r = 0; r < 8; ++r) {
                    acc[i][r] = fmaf(a[i].x, w[r].x, acc[i][r]);
                    acc[i][r] = fmaf(a[i].y, w[r].y, acc[i][r]);
                    acc[i][r] = fmaf(a[i].z, w[r].z, acc[i][r]);
                    acc[i][r] = fmaf(a[i].w, w[r].w, acc[i][r]);
                }
        }
        __syncthreads();  // protect LDS before next stage
    }

#pragma unroll
    for (int i = 0; i < 8; ++i) {
        int grow = bm0 + ty * 8 + i;
        if (grow >= nrows) continue;
        float4 o0 = make_float4(acc[i][0] + bv[0], acc[i][1] + bv[1],
                                acc[i][2] + bv[2], acc[i][3] + bv[3]);
        float4 o1 = make_float4(acc[i][4] + bv[4], acc[i][5] + bv[5],
                                acc[i][6] + bv[6], acc[i][7] + bv[7]);
        *reinterpret_cast<float4*>(&out[(size_t)grow * D + tx * 8]) = o0;
        *reinterpret_cast<float4*>(&out[(size_t)grow * D + tx * 8 + 4]) = o1;
    }
}

// ---------------- Aggregation: out[i] = t[i] + sum_{e: col==i} t[src[e]] ----------------
// Grid-strided persistent blocks (2 nodes per 256-thread block per iter).

#define AGG_BLOCKS 2048

__global__ __launch_bounds__(256) void aggregate_k(const float* __restrict__ t,
                                                   const int* __restrict__ start,
                                                   const int* __restrict__ esrc,
                                                   float* __restrict__ out, int do_relu) {
    const int d = threadIdx.x & 127;
    const int sub = threadIdx.x >> 7;  // 0..1 (wave-pair uniform)
    for (int node = blockIdx.x * 2 + sub; node < N_NODES; node += AGG_BLOCKS * 2) {
        int s = start[node], e = start[node + 1];
        float acc = t[(size_t)node * D + d];  // self loop
        int i = s;
        for (; i + 1 < e; i += 2) {
            int s0 = esrc[i], s1 = esrc[i + 1];
            float a = t[(size_t)s0 * D + d];
            float b = t[(size_t)s1 * D + d];
            acc += a + b;
        }
        if (i < e) acc += t[(size_t)esrc[i] * D + d];
        if (do_relu) acc = fmaxf(acc, 0.f);
        out[(size_t)node * D + d] = acc;
    }
}

// ---------------- Collapsed layer 4 + pool + head ----------------
// logit_g = (1/c_g) * sum_{i in g} [ s[i] + sum_{src->i} s[src] + (1+deg_i)*beta ] + bc
// where s[i] = h3[i] . v,  v = Wc @ W4,  beta = Wc . b4.

__global__ __launch_bounds__(128) void vbeta_k(const float* __restrict__ W4,
                                               const float* __restrict__ b4,
                                               const float* __restrict__ Wc,
                                               float* __restrict__ vbeta) {
    int k = threadIdx.x;
    float acc = 0.f;
    for (int j = 0; j < D; ++j) acc = fmaf(Wc[j], W4[j * D + k], acc);
    vbeta[k] = acc;
    __shared__ float red[128];
    red[k] = Wc[k] * b4[k];
    __syncthreads();
    for (int st = 64; st > 0; st >>= 1) {
        if (k < st) red[k] += red[k + st];
        __syncthreads();
    }
    if (k == 0) vbeta[D] = red[0];
}

__global__ __launch_bounds__(256) void matvec_k(const float* __restrict__ h,
                                                const float* __restrict__ vbeta,
                                                float* __restrict__ s) {
    int wid = threadIdx.x >> 6, lane = threadIdx.x & 63;
    int row = blockIdx.x * 4 + wid;
    const float2 hv = *reinterpret_cast<const float2*>(&h[(size_t)row * D + lane * 2]);
    const float2 vv = *reinterpret_cast<const float2*>(&vbeta[lane * 2]);
    float dot = fmaf(hv.x, vv.x, hv.y * vv.y);
#pragma unroll
    for (int d = 32; d > 0; d >>= 1) dot += __shfl_down(dot, d, 64);
    if (lane == 0) s[row] = dot;
}

__global__ __launch_bounds__(256) void sagg_k(const float* __restrict__ s,
                                              const int* __restrict__ start,
                                              const int* __restrict__ esrc,
                                              const float* __restrict__ vbeta,
                                              float* __restrict__ a) {
    int i = blockIdx.x * 256 + threadIdx.x;
    if (i >= N_NODES) return;
    int s0 = start[i], s1 = start[i + 1];
    float beta = vbeta[D];
    float acc = s[i] + (float)(1 + s1 - s0) * beta;
    for (int e = s0; e < s1; ++e) acc += s[esrc[e]];
    a[i] = acc;
}

__global__ __launch_bounds__(256) void spool_k(const float* __restrict__ a,
                                               const int* __restrict__ gstart,
                                               const float* __restrict__ bc,
                                               float* __restrict__ out) {
    int g = blockIdx.x;
    int lo = gstart[g], hi = gstart[g + 1];
    float acc = 0.f;
    for (int i = lo + threadIdx.x; i < hi; i += 256) acc += a[i];
    __shared__ float red[256];
    red[threadIdx.x] = acc;
    __syncthreads();
    for (int st = 128; st > 0; st >>= 1) {
        if (threadIdx.x < st) red[threadIdx.x] += red[threadIdx.x + st];
        __syncthreads();
    }
    if (threadIdx.x == 0) {
        float c = (float)max(hi - lo, 1);
        out[g] = 1.f / (1.f + expf(-(red[0] / c + bc[0])));
    }
}

// ---------------- Launch ----------------

extern "C" void kernel_launch(void* const* d_in, const int* in_sizes, int n_in,
                              void* d_out, int out_size, void* d_ws, size_t ws_size,
                              hipStream_t stream) {
    const float* x   = (const float*)d_in[0];
    const int* ei    = (const int*)d_in[1];
    const int* batch = (const int*)d_in[2];
    const float* W1  = (const float*)d_in[3];
    const float* b1  = (const float*)d_in[4];
    const float* W2  = (const float*)d_in[5];
    const float* b2  = (const float*)d_in[6];
    const float* W3  = (const float*)d_in[7];
    const float* b3  = (const float*)d_in[8];
    const float* W4  = (const float*)d_in[9];
    const float* b4  = (const float*)d_in[10];
    const float* Wc  = (const float*)d_in[11];
    const float* bc  = (const float*)d_in[12];
    float* out = (float*)d_out;

    const int* row = ei;             // sources
    const int* col = ei + N_EDGES;   // targets

    char* p = (char*)d_ws;
    float* t = (float*)p;      p += (size_t)N_NODES * D * 4;   // 51.2 MB
    float* h = (float*)p;      p += (size_t)N_NODES * D * 4;   // 51.2 MB
    int* esrc = (int*)p;       p += (size_t)N_EDGES * 4;
    int* cstart = (int*)p;     p += ((N_NODES + 1) * 4 + 15) / 16 * 16;
    int* cfill = (int*)p;      p += (size_t)N_NODES * 4;
    int* psum = (int*)p;       p += ((NBLK_SCAN + 3) / 4) * 16;
    int* gstart = (int*)p;     p += 256;

    // scalar-path scratch lives in t (free after layer-3 aggregate consumes it)
    float* vbeta = t;
    float* s_arr = t + 256;
    float* a_arr = t + 256 + N_NODES;

    // ---- CSR build ----
    hipMemsetAsync(cfill, 0, (size_t)N_NODES * 4, stream);
    count_deg_k<<<(N_EDGES + 255) / 256, 256, 0, stream>>>(col, cfill);
    partial_k<<<NBLK_SCAN, 256, 0, stream>>>(cfill, psum);
    scanpart_k<<<1, 512, 0, stream>>>(psum);
    scan_scatter_k<<<NBLK_SCAN, 256, 0, stream>>>(cfill, psum, cstart);
    hipMemsetAsync(cfill, 0, (size_t)N_NODES * 4, stream);
    fill_csr_k<<<(N_EDGES + 255) / 256, 256, 0, stream>>>(row, col, cstart, cfill, esrc);

    // ---- graph bounds ----
    bounds_k<<<1, 128, 0, stream>>>(batch, gstart);

    const int ggrid = (N_NODES + BM - 1) / BM;  // 782

    // ---- Layers 1-3 ----
    gemm_k<<<ggrid, 256, 0, stream>>>(x, W1, b1, t, N_NODES);
    aggregate_k<<<AGG_BLOCKS, 256, 0, stream>>>(t, cstart, esrc, h, 1);
    gemm_k<<<ggrid, 256, 0, stream>>>(h, W2, b2, t, N_NODES);
    aggregate_k<<<AGG_BLOCKS, 256, 0, stream>>>(t, cstart, esrc, h, 1);
    gemm_k<<<ggrid, 256, 0, stream>>>(h, W3, b3, t, N_NODES);
    aggregate_k<<<AGG_BLOCKS, 256, 0, stream>>>(t, cstart, esrc, h, 1);

    // ---- Collapsed layer 4 + pool + head (reads h = h3) ----
    vbeta_k<<<1, 128, 0, stream>>>(W4, b4, Wc, vbeta);
    matvec_k<<<N_NODES / 4, 256, 0, stream>>>(h, vbeta, s_arr);
    sagg_k<<<(N_NODES + 255) / 256, 256, 0, stream>>>(s_arr, cstart, esrc, vbeta, a_arr);
    spool_k<<<N_GRAPHS, 256, 0, stream>>>(a_arr, gstart, bc, out);
}